// Round 9
// baseline (586.004 us; speedup 1.0000x reference)
//
#include <hip/hip_runtime.h>

#define NTOK 4096
#define DIM  1024
#define HID  2816
#define NE   8
#define TLMAX 80
#define NT1  (44 * TLMAX)          // gemm1 tile-block region
#define N8W  2883584               // NE*HID*DIM/8 (uint4 outputs per weight tensor)
#define NCVT2 (N8W / 256)          // 11264 blocks for w2 cvt inside gemm1

typedef short  s8bf  __attribute__((ext_vector_type(8)));   // 8 bf16 in 4 VGPRs
typedef float  f32x4 __attribute__((ext_vector_type(4)));

__device__ __forceinline__ unsigned short f2bf(float f) {
    union { float f; unsigned u; } v; v.f = f;
    unsigned r = v.u + 0x7FFFu + ((v.u >> 16) & 1u);   // RNE
    return (unsigned short)(r >> 16);
}

__device__ __forceinline__ void gld16(const void* g, void* l) {
    __builtin_amdgcn_global_load_lds(
        (const __attribute__((address_space(1))) unsigned int*)g,
        (__attribute__((address_space(3))) unsigned int*)l, 16, 0, 0);
}

__device__ __forceinline__ void cvt8(const float4* __restrict__ s,
                                     uint4* __restrict__ d, int i) {
    float4 a = s[2 * i], b = s[2 * i + 1];
    union { unsigned short u[8]; uint4 v; } o;
    o.u[0] = f2bf(a.x); o.u[1] = f2bf(a.y); o.u[2] = f2bf(a.z); o.u[3] = f2bf(a.w);
    o.u[4] = f2bf(b.x); o.u[5] = f2bf(b.y); o.u[6] = f2bf(b.z); o.u[7] = f2bf(b.w);
    d[i] = o.v;
}

// inline tile map: from counts[] compute (e, m0, cnt, off_e) for tile_id, or invalid.
// Aligned mode (XCD pinning, tile%8==expert) when 8*maxmt<=TLMAX, else compact.
// All-register (unrolled scans), identical result in every block.
__device__ __forceinline__ bool tile_map(const int* __restrict__ counts, int tile_id,
                                         int& e, int& m0, int& cnt, int& off_e) {
    int c[NE];
#pragma unroll
    for (int i = 0; i < NE; ++i) c[i] = counts[i];
    int maxmt = 0, tot = 0;
#pragma unroll
    for (int i = 0; i < NE; ++i) {
        int n = (c[i] + 127) >> 7;
        tot += n;
        maxmt = n > maxmt ? n : maxmt;
    }
    int m = 0;
    bool valid;
    if (8 * maxmt <= TLMAX) {
        e = tile_id & 7; m = tile_id >> 3;
        valid = tile_id < 8 * maxmt;
    } else {
        valid = tile_id < tot;
        int run = 0; e = 0;
#pragma unroll
        for (int i = 0; i < NE; ++i) {
            int n = (c[i] + 127) >> 7;
            if (tile_id >= run && tile_id < run + n) { e = i; m = tile_id - run; }
            run += n;
        }
    }
    cnt = 0; off_e = 0; int acc = 0;
#pragma unroll
    for (int i = 0; i < NE; ++i) {
        if (i == e) { cnt = c[i]; off_e = acc; }
        acc += c[i];
    }
    valid = valid && (m < ((cnt + 127) >> 7));
    m0 = m << 7;
    return valid;
}

// ------- fused: w1/w3 f32->bf16 conversion + router (grid-split) -------------
__global__ __launch_bounds__(256) void cvt13_router_kernel(
    const float4* __restrict__ w1, const float4* __restrict__ w3,
    uint4* __restrict__ d1, uint4* __restrict__ d3, int ncvt,
    const float* __restrict__ x, const float* __restrict__ rw,
    unsigned short* __restrict__ xb, float* __restrict__ probs_buf,
    int* __restrict__ counts, int* __restrict__ idx_buf,
    float* __restrict__ wgt_buf, int* __restrict__ tok2eq) {
    int t = threadIdx.x;
    if ((int)blockIdx.x < ncvt) {
        int i = blockIdx.x * 256 + t;
        if (i < N8W) cvt8(w1, d1, i);
        else         cvt8(w3, d3, i - N8W);
        return;
    }

    __shared__ int lcnt[NE];
    __shared__ int gb[NE];
    if (t < NE) lcnt[t] = 0;
    __syncthreads();

    int g = t >> 4, lg = t & 15;
    int token = (blockIdx.x - ncvt) * 16 + g;
    const float4* xr = (const float4*)(x + (size_t)token * DIM);
    const float4* rw4 = (const float4*)rw;

    float p[NE];
#pragma unroll
    for (int e = 0; e < NE; ++e) p[e] = 0.f;

#pragma unroll 4
    for (int j = 0; j < 16; ++j) {
        int idx = lg + 16 * j;           // float4 index within row
        float4 xv = xr[idx];
        ushort4 o;
        o.x = f2bf(xv.x); o.y = f2bf(xv.y); o.z = f2bf(xv.z); o.w = f2bf(xv.w);
        ((ushort4*)xb)[(size_t)token * 256 + idx] = o;
#pragma unroll
        for (int e = 0; e < NE; ++e) {
            float4 wv = rw4[e * 256 + idx];
            p[e] += xv.x * wv.x + xv.y * wv.y + xv.z * wv.z + xv.w * wv.w;
        }
    }
#pragma unroll
    for (int e = 0; e < NE; ++e) {
        p[e] += __shfl_xor(p[e], 1, 64);
        p[e] += __shfl_xor(p[e], 2, 64);
        p[e] += __shfl_xor(p[e], 4, 64);
        p[e] += __shfl_xor(p[e], 8, 64);
    }

    int e0 = 0, e1 = 1; float cw0 = 0.f, cw1 = 0.f;
    int lp0 = 0, lp1 = 0;
    if (lg == 0) {
        float m = p[0];
#pragma unroll
        for (int e = 1; e < NE; ++e) m = fmaxf(m, p[e]);
        float pr[NE], s = 0.f;
#pragma unroll
        for (int e = 0; e < NE; ++e) { pr[e] = expf(p[e] - m); s += pr[e]; }
        float inv = 1.f / s;
#pragma unroll
        for (int e = 0; e < NE; ++e) { pr[e] *= inv; probs_buf[token * NE + e] = pr[e]; }
        e0 = 0;
#pragma unroll
        for (int e = 1; e < NE; ++e) if (pr[e] > pr[e0]) e0 = e;
        e1 = (e0 == 0) ? 1 : 0;
#pragma unroll
        for (int e = 0; e < NE; ++e) if (e != e0 && pr[e] > pr[e1]) e1 = e;
        float s2 = fmaxf(pr[e0] + pr[e1], 1e-9f);
        cw0 = pr[e0] / s2; cw1 = pr[e1] / s2;
        lp0 = atomicAdd(&lcnt[e0], 1);
        lp1 = atomicAdd(&lcnt[e1], 1);
    }
    __syncthreads();
    if (t < NE) gb[t] = atomicAdd(&counts[t], lcnt[t]);
    __syncthreads();
    if (lg == 0) {
        int q0 = gb[e0] + lp0, q1 = gb[e1] + lp1;
        idx_buf[e0 * NTOK + q0] = token; wgt_buf[e0 * NTOK + q0] = cw0;
        idx_buf[e1 * NTOK + q1] = token; wgt_buf[e1 * NTOK + q1] = cw1;
        tok2eq[2 * token]     = (e0 << 12) | q0;
        tok2eq[2 * token + 1] = (e1 << 12) | q1;
    }
}

// ---------------- GEMM1 (+w2 cvt in trailing blocks) -------------------------
// tile: 128 tokens x 64 hid; 2-phase prefetch double-buffer; both-sides swizzle.
__global__ __launch_bounds__(256, 2) void gemm1_kernel(
    const unsigned short* __restrict__ xb,
    const unsigned short* __restrict__ w1b,
    const unsigned short* __restrict__ w3b,
    const int* __restrict__ counts,
    const int* __restrict__ idx_buf,
    unsigned short* __restrict__ h,
    const float4* __restrict__ w2, uint4* __restrict__ d2) {
    int t = threadIdx.x;
    int bid = blockIdx.x;
    if (bid >= NT1) {                       // w2 f32->bf16 conversion region
        int i = (bid - NT1) * 256 + t;      // exactly N8W
        cvt8(w2, d2, i);
        return;
    }
    int tile_id = bid % TLMAX;
    int n_t = bid / TLMAX;                  // 0..43
    int e, m0, cnt, off_e;
    if (!tile_map(counts, tile_id, e, m0, cnt, off_e)) return;
    int n0 = n_t * 64;

    __shared__ unsigned short As[2][128 * 64];   // 2 x 16 KB
    __shared__ unsigned short Bs[2][128 * 64];   // 2 x 16 KB

    int s = t & 7, sub = t >> 3;              // slot (16B units), subrow
    const unsigned short* paA[4];
    const unsigned short* pbB[4];
#pragma unroll
    for (int p = 0; p < 4; ++p) {
        int row = p * 32 + sub;               // 0..127
        int rr = m0 + row;
        int tok = idx_buf[e * NTOK + (rr < cnt ? rr : cnt - 1)];
        paA[p] = xb + (size_t)tok * DIM + ((s ^ (row & 7)) * 8);
        int hr = n0 + (row & 63);
        const unsigned short* base = (row < 64) ? w1b : w3b;
        pbB[p] = base + ((size_t)e * HID + hr) * DIM + ((s ^ (row & 7)) * 8);
    }

#define STAGE_G1(cbuf, kk) do {                                             \
    _Pragma("unroll")                                                       \
    for (int p = 0; p < 4; ++p) {                                           \
        gld16(paA[p] + (kk), (char*)As + (cbuf) * 16384 + p * 4096 + t * 16); \
        gld16(pbB[p] + (kk), (char*)Bs + (cbuf) * 16384 + p * 4096 + t * 16); \
    } } while (0)

    f32x4 acc[2][8];
#pragma unroll
    for (int m = 0; m < 2; ++m)
#pragma unroll
        for (int n = 0; n < 8; ++n) acc[m][n] = (f32x4){0.f, 0.f, 0.f, 0.f};

    int lane = t & 63, wid = t >> 6;
    int lr = lane & 15, hi = lane >> 4;       // hi 0..3
    int swz = (lr & 7) << 4;
    int arow0 = (wid * 32 + lr) * 128;
    int arow1 = (wid * 32 + 16 + lr) * 128;

    STAGE_G1(0, 0);
    __syncthreads();
    int cur = 0;
    for (int kk = 0; kk < DIM; kk += 64) {
        if (kk + 64 < DIM) STAGE_G1(cur ^ 1, kk + 64);   // prefetch next tile
        const char* Ab = (const char*)As + cur * 16384;
        const char* Bb = (const char*)Bs + cur * 16384;
#pragma unroll
        for (int ks = 0; ks < 2; ++ks) {
            int koff = (ks * 64 + hi * 16) ^ swz;
            s8bf a[2], b[8];
            a[0] = *(const s8bf*)(Ab + arow0 + koff);
            a[1] = *(const s8bf*)(Ab + arow1 + koff);
#pragma unroll
            for (int n = 0; n < 8; ++n)
                b[n] = *(const s8bf*)(Bb + (n * 16 + lr) * 128 + koff);
#pragma unroll
            for (int m = 0; m < 2; ++m)
#pragma unroll
                for (int n = 0; n < 8; ++n)
                    acc[m][n] = __builtin_amdgcn_mfma_f32_16x16x32_bf16(a[m], b[n], acc[m][n], 0, 0, 0);
        }
        __syncthreads();                     // staged data landed + reads done
        cur ^= 1;
    }

    int rq = hi * 4;
#pragma unroll
    for (int m = 0; m < 2; ++m)
#pragma unroll
        for (int n = 0; n < 4; ++n) {
            f32x4 g4 = acc[m][n], u4 = acc[m][n + 4];
#pragma unroll
            for (int r = 0; r < 4; ++r) {
                int row = m0 + wid * 32 + m * 16 + rq + r;
                if (row < cnt) {
                    float gg = g4[r], u = u4[r];
                    float hv = (gg / (1.f + __expf(-gg))) * u;    // silu(g)*u
                    h[(size_t)(off_e + row) * HID + (n0 + n * 16 + lr)] = f2bf(hv);
                }
            }
        }
}

// ---------------- GEMM2: y[gslot] = wgt * (h @ w2^T), 2-phase ----------------
__global__ __launch_bounds__(256, 2) void gemm2_kernel(
    const unsigned short* __restrict__ h,
    const unsigned short* __restrict__ w2b,
    const int* __restrict__ counts,
    const float* __restrict__ wgt_buf,
    float* __restrict__ y) {
    int t = threadIdx.x;
    int tile_id = blockIdx.x % TLMAX;
    int n_t = blockIdx.x / TLMAX;          // 0..7
    int e, m0, cnt, off_e;
    if (!tile_map(counts, tile_id, e, m0, cnt, off_e)) return;
    int n0 = n_t * 128;

    __shared__ unsigned short As[2][128 * 64];
    __shared__ unsigned short Bs[2][128 * 64];

    int s = t & 7, sub = t >> 3;
    const unsigned short* paA[4];
    const unsigned short* pbB[4];
#pragma unroll
    for (int p = 0; p < 4; ++p) {
        int row = p * 32 + sub;
        int rr = m0 + row;
        int grow = off_e + (rr < cnt ? rr : cnt - 1);
        paA[p] = h + (size_t)grow * HID + ((s ^ (row & 7)) * 8);
        pbB[p] = w2b + ((size_t)e * DIM + n0 + row) * HID + ((s ^ (row & 7)) * 8);
    }

#define STAGE_G2(cbuf, kk) do {                                             \
    _Pragma("unroll")                                                       \
    for (int p = 0; p < 4; ++p) {                                           \
        gld16(paA[p] + (kk), (char*)As + (cbuf) * 16384 + p * 4096 + t * 16); \
        gld16(pbB[p] + (kk), (char*)Bs + (cbuf) * 16384 + p * 4096 + t * 16); \
    } } while (0)

    f32x4 acc[4][4];
#pragma unroll
    for (int m = 0; m < 4; ++m)
#pragma unroll
        for (int n = 0; n < 4; ++n) acc[m][n] = (f32x4){0.f, 0.f, 0.f, 0.f};

    int lane = t & 63, wid = t >> 6;
    int wr = wid >> 1, wc = wid & 1;
    int lr = lane & 15, hi = lane >> 4;
    int swz = (lr & 7) << 4;

    STAGE_G2(0, 0);
    __syncthreads();
    int cur = 0;
    for (int kk = 0; kk < HID; kk += 64) {
        if (kk + 64 < HID) STAGE_G2(cur ^ 1, kk + 64);
        const char* Ab = (const char*)As + cur * 16384;
        const char* Bb = (const char*)Bs + cur * 16384;
#pragma unroll
        for (int ks = 0; ks < 2; ++ks) {
            int koff = (ks * 64 + hi * 16) ^ swz;
            s8bf a[4], b[4];
#pragma unroll
            for (int m = 0; m < 4; ++m)
                a[m] = *(const s8bf*)(Ab + (wr * 64 + m * 16 + lr) * 128 + koff);
#pragma unroll
            for (int n = 0; n < 4; ++n)
                b[n] = *(const s8bf*)(Bb + (wc * 64 + n * 16 + lr) * 128 + koff);
#pragma unroll
            for (int m = 0; m < 4; ++m)
#pragma unroll
                for (int n = 0; n < 4; ++n)
                    acc[m][n] = __builtin_amdgcn_mfma_f32_16x16x32_bf16(a[m], b[n], acc[m][n], 0, 0, 0);
        }
        __syncthreads();
        cur ^= 1;
    }

    int rq = hi * 4;
#pragma unroll
    for (int m = 0; m < 4; ++m) {
#pragma unroll
        for (int r = 0; r < 4; ++r) {
            int row = m0 + wr * 64 + m * 16 + rq + r;
            if (row < cnt) {
                float wgt = wgt_buf[e * NTOK + row];
                float* yrow = y + (size_t)(off_e + row) * DIM + n0 + wc * 64;
#pragma unroll
                for (int n = 0; n < 4; ++n)
                    yrow[n * 16 + lr] = wgt * acc[m][n][r];
            }
        }
    }
}

// -------- combine (out[tok] = y[slot0]+y[slot1]) + aux loss (last block) -----
__global__ __launch_bounds__(256) void combine_aux_kernel(
    const float4* __restrict__ y, const int* __restrict__ tok2eq,
    const int* __restrict__ counts, float4* __restrict__ out,
    const float* __restrict__ probs_buf, float* __restrict__ out_aux) {
    int t = threadIdx.x;
    if (blockIdx.x == NTOK) {               // aux block
        __shared__ float sd[256 * 16];
        float acc[16];
#pragma unroll
        for (int j = 0; j < 16; ++j) acc[j] = 0.f;
        for (int tok = t; tok < NTOK; tok += 256) {
#pragma unroll
            for (int e = 0; e < NE; ++e) {
                float p = probs_buf[tok * NE + e];
                acc[e] += p;
                acc[NE + e] += (p > 0.125f) ? 1.f : 0.f;
            }
        }
#pragma unroll
        for (int j = 0; j < 16; ++j) sd[t * 16 + j] = acc[j];
        __syncthreads();
        for (int ss = 128; ss > 0; ss >>= 1) {
            if (t < ss) {
#pragma unroll
                for (int j = 0; j < 16; ++j) sd[t * 16 + j] += sd[(t + ss) * 16 + j];
            }
            __syncthreads();
        }
        if (t == 0) {
            float aux = 0.f;
            for (int e = 0; e < NE; ++e)
                aux += (sd[e] / (float)NTOK) * (sd[NE + e] / (float)NTOK);
            out_aux[0] = aux * (float)(NE * NE);
        }
        return;
    }
    int tok = blockIdx.x;
    int v0 = tok2eq[2 * tok], v1 = tok2eq[2 * tok + 1];
    int e0 = v0 >> 12, e1 = v1 >> 12;
    int off0 = 0, off1 = 0, acc = 0;
#pragma unroll
    for (int e = 0; e < NE; ++e) {
        int c = counts[e];
        if (e == e0) off0 = acc;
        if (e == e1) off1 = acc;
        acc += c;
    }
    int g0 = off0 + (v0 & 4095);
    int g1 = off1 + (v1 & 4095);
    out[(size_t)tok * 256 + t] = y[(size_t)g0 * 256 + t] + y[(size_t)g1 * 256 + t];
}

extern "C" void kernel_launch(void* const* d_in, const int* in_sizes, int n_in,
                              void* d_out, int out_size, void* d_ws, size_t ws_size,
                              hipStream_t stream) {
    const float* x  = (const float*)d_in[0];
    const float* rw = (const float*)d_in[1];
    const float* w1 = (const float*)d_in[2];
    const float* w2 = (const float*)d_in[3];
    const float* w3 = (const float*)d_in[4];
    float* out = (float*)d_out;

    char* ws = (char*)d_ws;
    size_t o = 0;
    unsigned short* xb   = (unsigned short*)(ws + o); o += (size_t)NTOK * DIM * 2;
    unsigned short* w1b  = (unsigned short*)(ws + o); o += (size_t)NE * HID * DIM * 2;
    unsigned short* w3b  = (unsigned short*)(ws + o); o += (size_t)NE * HID * DIM * 2;
    unsigned short* w2b  = (unsigned short*)(ws + o); o += (size_t)NE * DIM * HID * 2;
    unsigned short* hbuf = (unsigned short*)(ws + o); o += (size_t)NTOK * 2 * HID * 2;
    int*   counts   = (int*)(ws + o);   o += 256;
    int*   idx_buf  = (int*)(ws + o);   o += (size_t)NE * NTOK * 4;
    float* wgt_buf  = (float*)(ws + o); o += (size_t)NE * NTOK * 4;
    float* probs_buf= (float*)(ws + o); o += (size_t)NTOK * NE * 4;
    int*   tok2eq   = (int*)(ws + o);   o += (size_t)NTOK * 2 * 4;
    // y-buffer aliases w1b (dead after gemm1; rewritten by cvt every launch)
    float* ybuf = (float*)w1b;          // NTOK*2*DIM f32 = 33.5 MB <= 46.1 MB

    hipMemsetAsync(counts, 0, 256, stream);

    int ncvt13 = 2 * N8W / 256;         // 22528 blocks for w1+w3 cvt
    cvt13_router_kernel<<<ncvt13 + NTOK / 16, 256, 0, stream>>>(
        (const float4*)w1, (const float4*)w3,
        (uint4*)w1b, (uint4*)w3b, ncvt13,
        x, rw, xb, probs_buf, counts, idx_buf, wgt_buf, tok2eq);

    gemm1_kernel<<<NT1 + NCVT2, 256, 0, stream>>>(
        xb, w1b, w3b, counts, idx_buf, hbuf,
        (const float4*)w2, (uint4*)w2b);

    gemm2_kernel<<<(DIM / 128) * TLMAX, 256, 0, stream>>>(
        hbuf, w2b, counts, wgt_buf, ybuf);

    combine_aux_kernel<<<NTOK + 1, 256, 0, stream>>>(
        (const float4*)ybuf, tok2eq, counts, (float4*)out, probs_buf,
        out + ((size_t)out_size - 1));
}